// Round 12
// baseline (1286.770 us; speedup 1.0000x reference)
//
#include <hip/hip_runtime.h>

#define N_NODES 50000
#define N_EDGES 800000
#define R_REL   8
#define NR      (N_NODES * R_REL)        // 400000
#define SCAN_CHUNK 2048
#define SCAN_NBLK  ((NR + SCAN_CHUNK - 1) / SCAN_CHUNK)   // 196

// bucketed CSR build
#define NBKT    196                      // buckets of 256 dst-nodes
#define BNSH    8                        // dst>>8 -> bucket
#define BKEYS   2048                     // keys per bucket (256 nodes x 8 rels)
#define BCAP    5120                     // record capacity per bucket (mean 4083, +16 sigma)
#define SLAB    2048                     // edges per bin-block
#define BINBLK  ((N_EDGES + SLAB - 1) / SLAB)  // 391

typedef float  f32x4  __attribute__((ext_vector_type(4)));
typedef __bf16 bf16x8 __attribute__((ext_vector_type(8)));

__device__ __forceinline__ unsigned short f2bf(float f) {
    unsigned int u = __float_as_uint(f);
    u = (u + 0x7FFFu + ((u >> 16) & 1u)) >> 16;   // RNE
    return (unsigned short)u;
}
__device__ __forceinline__ float bflo(unsigned int u) { return __uint_as_float(u << 16); }
__device__ __forceinline__ float bfhi(unsigned int u) { return __uint_as_float(u & 0xFFFF0000u); }

// 32 LDS fp32 atomic adds for one 32-feat quarter (banks ~2-way with +1-word pad)
__device__ __forceinline__ void ds_acc32(float* d, uint4 u0, uint4 u1, uint4 u2, uint4 u3) {
    atomicAdd(d + 0,  bflo(u0.x)); atomicAdd(d + 1,  bfhi(u0.x));
    atomicAdd(d + 2,  bflo(u0.y)); atomicAdd(d + 3,  bfhi(u0.y));
    atomicAdd(d + 4,  bflo(u0.z)); atomicAdd(d + 5,  bfhi(u0.z));
    atomicAdd(d + 6,  bflo(u0.w)); atomicAdd(d + 7,  bfhi(u0.w));
    atomicAdd(d + 8,  bflo(u1.x)); atomicAdd(d + 9,  bfhi(u1.x));
    atomicAdd(d + 10, bflo(u1.y)); atomicAdd(d + 11, bfhi(u1.y));
    atomicAdd(d + 12, bflo(u1.z)); atomicAdd(d + 13, bfhi(u1.z));
    atomicAdd(d + 14, bflo(u1.w)); atomicAdd(d + 15, bfhi(u1.w));
    atomicAdd(d + 16, bflo(u2.x)); atomicAdd(d + 17, bfhi(u2.x));
    atomicAdd(d + 18, bflo(u2.y)); atomicAdd(d + 19, bfhi(u2.y));
    atomicAdd(d + 20, bflo(u2.z)); atomicAdd(d + 21, bfhi(u2.z));
    atomicAdd(d + 22, bflo(u2.w)); atomicAdd(d + 23, bfhi(u2.w));
    atomicAdd(d + 24, bflo(u3.x)); atomicAdd(d + 25, bfhi(u3.x));
    atomicAdd(d + 26, bflo(u3.y)); atomicAdd(d + 27, bfhi(u3.y));
    atomicAdd(d + 28, bflo(u3.z)); atomicAdd(d + 29, bfhi(u3.z));
    atomicAdd(d + 30, bflo(u3.w)); atomicAdd(d + 31, bfhi(u3.w));
}

// ---------------- bucketed CSR build ----------------

__global__ __launch_bounds__(256) void k_binA(
    const int* __restrict__ src, const int* __restrict__ dst,
    const int* __restrict__ et, int* __restrict__ gcur,
    uint2* __restrict__ gbin)
{
    __shared__ int hist[NBKT];
    __shared__ int base[NBKT];
    const int t = threadIdx.x;
    const int e0 = blockIdx.x * SLAB;
    for (int i = t; i < NBKT; i += 256) hist[i] = 0;
    __syncthreads();
#pragma unroll
    for (int i = 0; i < SLAB / 256; ++i) {
        int e = e0 + i * 256 + t;
        if (e < N_EDGES) atomicAdd(&hist[dst[e] >> BNSH], 1);
    }
    __syncthreads();
    for (int i = t; i < NBKT; i += 256) {
        int h = hist[i];
        base[i] = (h > 0) ? atomicAdd(&gcur[i], h) : 0;
        hist[i] = 0;   // reuse as sub-cursor
    }
    __syncthreads();
#pragma unroll
    for (int i = 0; i < SLAB / 256; ++i) {
        int e = e0 + i * 256 + t;
        if (e < N_EDGES) {
            int d = dst[e];
            int b = d >> BNSH;
            int sub = atomicAdd(&hist[b], 1);
            gbin[b * BCAP + base[b] + sub] =
                make_uint2((unsigned)src[e], (unsigned)(d * 8 + et[e]));
        }
    }
}

__global__ __launch_bounds__(256) void k_bcount(
    const int* __restrict__ gcur, const uint2* __restrict__ gbin,
    int* __restrict__ cnt)
{
    __shared__ int lc[BKEYS];
    const int t = threadIdx.x;
    const int b = blockIdx.x;
    for (int i = t; i < BKEYS; i += 256) lc[i] = 0;
    __syncthreads();
    const int n = gcur[b];
    const uint2* rec = gbin + (size_t)b * BCAP;
    const int kbase = b * BKEYS;
    for (int j = t; j < n; j += 256)
        atomicAdd(&lc[rec[j].y - kbase], 1);
    __syncthreads();
    for (int i = t; i < BKEYS; i += 256) {
        int k = kbase + i;
        if (k < NR) cnt[k] = lc[i];
    }
}

// scatter packed: src | (tile-local pair << 16); tile = 16 nodes x 8 rels = 128
__global__ __launch_bounds__(256) void k_bscat(
    const int* __restrict__ gcur, const uint2* __restrict__ gbin,
    const int* __restrict__ offs, int* __restrict__ srcSp)
{
    __shared__ int cur[BKEYS];
    const int t = threadIdx.x;
    const int b = blockIdx.x;
    for (int i = t; i < BKEYS; i += 256) cur[i] = 0;
    __syncthreads();
    const int n = gcur[b];
    const uint2* rec = gbin + (size_t)b * BCAP;
    const int kbase = b * BKEYS;
    for (int j = t; j < n; j += 256) {
        uint2 r = rec[j];
        int sub = atomicAdd(&cur[r.y - kbase], 1);
        srcSp[offs[r.y] + sub] = (int)((r.x & 0xFFFFu) | ((r.y & 127u) << 16));
    }
}

// ---------------- scans (exclusive prefix over cnt) ----------------

__global__ void k_scan1(const int* __restrict__ cnt, int* __restrict__ offs,
                        int* __restrict__ bsum) {
    __shared__ int sd[256];
    int t = threadIdx.x;
    int base = blockIdx.x * SCAN_CHUNK + t * 8;
    int v[8];
    int tot = 0;
#pragma unroll
    for (int i = 0; i < 8; i++) {
        int idx = base + i;
        int xv = (idx < NR) ? cnt[idx] : 0;
        v[i] = tot;
        tot += xv;
    }
    sd[t] = tot;
    __syncthreads();
    for (int off = 1; off < 256; off <<= 1) {
        int y = (t >= off) ? sd[t - off] : 0;
        __syncthreads();
        sd[t] += y;
        __syncthreads();
    }
    int excl = sd[t] - tot;
#pragma unroll
    for (int i = 0; i < 8; i++) {
        int idx = base + i;
        if (idx < NR) offs[idx] = v[i] + excl;
    }
    if (t == 255) bsum[blockIdx.x] = sd[255];
}

__global__ void k_scan2(const int* __restrict__ bsum, int* __restrict__ bsum2) {
    __shared__ int sd[256];
    int t = threadIdx.x;
    int v = (t < SCAN_NBLK) ? bsum[t] : 0;
    sd[t] = v;
    __syncthreads();
    for (int off = 1; off < 256; off <<= 1) {
        int y = (t >= off) ? sd[t - off] : 0;
        __syncthreads();
        sd[t] += y;
        __syncthreads();
    }
    bsum2[t] = sd[t] - v;
}

__global__ void k_scan3(int* __restrict__ offs, const int* __restrict__ bsum2) {
    int t = threadIdx.x;
    int b = blockIdx.x;
    int add = bsum2[b];
    int base = b * SCAN_CHUNK + t * 8;
#pragma unroll
    for (int i = 0; i < 8; i++) {
        int idx = base + i;
        if (idx < NR) offs[idx] += add;
    }
    if (b == 0 && t == 0) offs[NR] = N_EDGES;
}

// ---------------- converts ----------------

__global__ void k_cvt_x(const float* __restrict__ x, unsigned short* __restrict__ xb, int n4) {
    int i = blockIdx.x * 256 + threadIdx.x;
    if (i < n4) {
        float4 v = *(const float4*)(x + (size_t)i * 4);
        ushort4 o;
        o.x = f2bf(v.x); o.y = f2bf(v.y); o.z = f2bf(v.z); o.w = f2bf(v.w);
        *(ushort4*)(xb + (size_t)i * 4) = o;
    }
}

// Fragment-ordered weight packing:
// WtP[(((seg*4 + kk)*NBt + nb)*64 + lane)*8 + j] = B[seg][n=nb*16+(lane&15)][k=kk*32+(lane>>4)*8+j]
#define W1_ELEMS (9 * 128 * 128)   // NBt=8
#define W2_ELEMS (9 * 64 * 128)    // NBt=4
__global__ void k_wprep_all(const float* __restrict__ root1, const float* __restrict__ W1,
                            const float* __restrict__ root2, const float* __restrict__ W2,
                            unsigned short* __restrict__ Wt1, unsigned short* __restrict__ Wt2) {
    int idx = blockIdx.x * 256 + threadIdx.x;
    if (idx < W1_ELEMS) {
        int j    = idx & 7;
        int lane = (idx >> 3) & 63;
        int r    = idx >> 9;
        int nb   = r & 7;        // NBt = 8
        int r2   = r >> 3;
        int kk   = r2 & 3;
        int seg  = r2 >> 2;
        int k = kk * 32 + (lane >> 4) * 8 + j;
        int n = nb * 16 + (lane & 15);
        float v = (seg == 0) ? root1[k * 128 + n] : W1[((seg - 1) * 128 + k) * 128 + n];
        Wt1[idx] = f2bf(v);
    } else if (idx < W1_ELEMS + W2_ELEMS) {
        int i2   = idx - W1_ELEMS;
        int j    = i2 & 7;
        int lane = (i2 >> 3) & 63;
        int r    = i2 >> 9;
        int nb   = r & 3;        // NBt = 4
        int r2   = r >> 2;
        int kk   = r2 & 3;
        int seg  = r2 >> 2;
        int k = kk * 32 + (lane >> 4) * 8 + j;
        int n = nb * 16 + (lane & 15);
        float v = (seg == 0) ? root2[k * 64 + n] : W2[((seg - 1) * 128 + k) * 64 + n];
        Wt2[i2] = f2bf(v);
    }
}

// ---------------- fused edge-parallel aggregate + MFMA layer ----------------
// Block = 512 threads, 16-node tile (128 pairs), 3125 blocks exact.
// The tile's edges are CONTIGUOUS in srcSp (CSR pair-ordered, tiles 128-pair
// aligned); each record carries its tile-local pair in bits 16..22.
// Phase 1: zero fp32 acc[128][132] (quarter q at +q*33: ds_add bank =
//   (4lp+q+k)&31 ~2-way). Phase 2: items (edge,quarter) strided over 512
//   threads: 4x uint4 row load + 32 ds_add_f32 — balanced, no stragglers.
// Phase 3: convert+mean -> bf16 As[9][16][136] OVERLAID on acc (barrier-
//   separated); root rows prefetched to regs then staged to As[0].
// Phase 4: MFMA with fragment-ordered B (1 coalesced txn per B-frag).

template <int FOUT, bool RELU, bool OUT_BF16>
__global__ __launch_bounds__(512) void k_fused(
    const unsigned short* __restrict__ xin,  // [N,128] bf16
    const unsigned short* __restrict__ WtP,  // fragment-ordered weights
    const float* __restrict__ bias,          // [FOUT]
    const int* __restrict__ offs,            // [NR+1]
    const int* __restrict__ srcSp,           // [E] packed src|lp
    unsigned short* __restrict__ outb,       // [N,FOUT] bf16 (if OUT_BF16)
    float* __restrict__ outf)                // [N,FOUT] fp32 (else)
{
    constexpr int NBt = FOUT / 16;           // 8 (L1) / 4 (L2)
    __shared__ __align__(16) float accs[128 * 132];          // 67584 B
    unsigned short* As = (unsigned short*)accs;              // [9][16][136] overlay

    const int t = threadIdx.x;
    const int node0 = blockIdx.x * 16;
    const int pair0 = node0 * 8;

    // ---- phase 0: zero acc ----
    {
        float4 z = make_float4(0.f, 0.f, 0.f, 0.f);
        float4* p = (float4*)accs;
#pragma unroll
        for (int i = 0; i < 9; ++i) {          // 9*512 = 4608 >= 4224
            int idx = i * 512 + t;
            if (idx < 128 * 33) p[idx] = z;
        }
    }
    const int beg0 = offs[pair0];
    const int end0 = offs[pair0 + 128];
    __syncthreads();

    // ---- phase 1: edge-parallel accumulate ----
    {
        const int nI = (end0 - beg0) * 4;
        for (int idx = t; idx < nI; idx += 512) {
            int e = beg0 + (idx >> 2);
            int q = idx & 3;
            unsigned v = (unsigned)srcSp[e];
            int s  = (int)(v & 0xFFFFu);
            int lp = (int)((v >> 16) & 127u);
            const uint4* p = (const uint4*)(xin + (size_t)s * 128 + q * 32);
            uint4 u0 = p[0], u1 = p[1], u2 = p[2], u3 = p[3];
            ds_acc32(accs + lp * 132 + q * 33, u0, u1, u2, u3);
        }
    }
    __syncthreads();

    // ---- phase 2: read acc + deg; prefetch root rows ----
    uint4 rr0, rr1;
    if (t < 128) {
        const int sr = t >> 3, sp = t & 7;
        const uint4* src = (const uint4*)(xin + (size_t)(node0 + sr) * 128 + sp * 16);
        rr0 = src[0]; rr1 = src[1];
    }
    const int lp = t >> 2;
    const int q  = t & 3;
    float a[32];
    {
        const float* sp2 = accs + lp * 132 + q * 33;
#pragma unroll
        for (int i = 0; i < 32; ++i) a[i] = sp2[i];
    }
    int deg;
    {
        int pr = pair0 + lp;
        deg = offs[pr + 1] - offs[pr];
    }
    __syncthreads();   // all acc reads done -> safe to overwrite with As

    // ---- phase 3: write bf16 As (overlay) + root slab ----
    {
        float scl = 1.f / (float)(deg > 1 ? deg : 1);
        unsigned int pk[16];
#pragma unroll
        for (int i = 0; i < 16; ++i)
            pk[i] = (unsigned int)f2bf(a[i * 2] * scl) |
                    ((unsigned int)f2bf(a[i * 2 + 1] * scl) << 16);
        const int rel = lp & 7, nl = lp >> 3;
        uint4* d = (uint4*)(As + ((size_t)(1 + rel) * 16 + nl) * 136 + q * 32);
        d[0] = make_uint4(pk[0],  pk[1],  pk[2],  pk[3]);
        d[1] = make_uint4(pk[4],  pk[5],  pk[6],  pk[7]);
        d[2] = make_uint4(pk[8],  pk[9],  pk[10], pk[11]);
        d[3] = make_uint4(pk[12], pk[13], pk[14], pk[15]);
    }
    if (t < 128) {
        const int sr = t >> 3, sp = t & 7;
        uint4* d = (uint4*)(As + (size_t)sr * 136 + sp * 16);
        d[0] = rr0; d[1] = rr1;
    }
    __syncthreads();

    // ---- phase 4: MFMA, wave w owns col-tile w ----
    const int lane = t & 63;
    const int w = t >> 6;
    if (w >= NBt) return;            // FOUT=64: waves 4-7 done (no barrier after)
    const int quad = lane >> 4;
    const int tc = lane & 15;

    f32x4 acc4 = (f32x4){0.f, 0.f, 0.f, 0.f};
    const bf16x8* Bp = (const bf16x8*)WtP;

#pragma unroll
    for (int seg = 0; seg < 9; ++seg) {
        const unsigned short* Arow = As + (size_t)(seg * 16 + tc) * 136;
#pragma unroll
        for (int kk = 0; kk < 4; ++kk) {
            bf16x8 af = *(const bf16x8*)(Arow + kk * 32 + quad * 8);
            bf16x8 bf = Bp[((seg * 4 + kk) * NBt + w) * 64 + lane];
            acc4 = __builtin_amdgcn_mfma_f32_16x16x32_bf16(af, bf, acc4, 0, 0, 0);
        }
    }

    // epilogue: D layout col = lane&15, row = quad*4 + reg
    const int col = w * 16 + tc;
    const float bs = bias[col];
#pragma unroll
    for (int i = 0; i < 4; ++i) {
        int r = node0 + quad * 4 + i;
        float v = acc4[i] + bs;
        if (RELU) v = fmaxf(v, 0.f);
        if (OUT_BF16) outb[(size_t)r * FOUT + col] = f2bf(v);
        else          outf[(size_t)r * FOUT + col] = v;
    }
}

// ---------------- launch ----------------

extern "C" void kernel_launch(void* const* d_in, const int* in_sizes, int n_in,
                              void* d_out, int out_size, void* d_ws, size_t ws_size,
                              hipStream_t stream) {
    const float* x     = (const float*)d_in[0];
    const int*   ei    = (const int*)d_in[1];  // [2][E]: row0=src, row1=dst
    const int*   et    = (const int*)d_in[2];  // [E]
    const float* W1    = (const float*)d_in[3];
    const float* root1 = (const float*)d_in[4];
    const float* b1    = (const float*)d_in[5];
    const float* W2    = (const float*)d_in[6];
    const float* root2 = (const float*)d_in[7];
    const float* b2    = (const float*)d_in[8];
    float* out = (float*)d_out;

    int* ws     = (int*)d_ws;
    int* cnt    = ws;                  // NR        (reused for Wt1 after scan1)
    int* offs   = cnt + NR;            // NR+128
    int* wt2buf = offs + NR + 128;     // NR        (holds Wt2, 144 KB)
    int* bsum   = wt2buf + NR;         // 256
    int* bsum2  = bsum + 256;          // 256
    int* gcur   = bsum2 + 256;         // 256
    int* srcSp  = gcur + 256;          // E (packed src | lp<<16)
    unsigned short* xb  = (unsigned short*)(srcSp + N_EDGES); // [N,128] bf16 (12.8 MB)
    unsigned short* hb  = xb + (size_t)N_NODES * 128;         // [N,128] bf16 (12.8 MB)
    uint2* gbin = (uint2*)(hb + (size_t)N_NODES * 128);       // 8.03 MB
    unsigned short* Wt1 = (unsigned short*)cnt;
    unsigned short* Wt2 = (unsigned short*)wt2buf;
    // total ws usage: ~8 MB ints + 12.8 + 12.8 + 8 = ~42 MB (ws = 256 MiB)

    hipMemsetAsync(gcur, 0, 256 * sizeof(int), stream);
    k_binA<<<BINBLK, 256, 0, stream>>>(ei, ei + N_EDGES, et, gcur, gbin);
    k_bcount<<<NBKT, 256, 0, stream>>>(gcur, gbin, cnt);
    k_scan1<<<SCAN_NBLK, 256, 0, stream>>>(cnt, offs, bsum);
    k_scan2<<<1, 256, 0, stream>>>(bsum, bsum2);
    k_scan3<<<SCAN_NBLK, 256, 0, stream>>>(offs, bsum2);
    k_bscat<<<NBKT, 256, 0, stream>>>(gcur, gbin, offs, srcSp);

    // cnt dead after scan1 -> Wt1 overwrites; wt2buf never aliased
    k_wprep_all<<<(W1_ELEMS + W2_ELEMS + 255) / 256, 256, 0, stream>>>(
        root1, W1, root2, W2, Wt1, Wt2);
    k_cvt_x<<<(N_NODES * 32 + 255) / 256, 256, 0, stream>>>(x, xb, N_NODES * 32);

    const int NT = N_NODES / 16;  // 3125 exactly

    k_fused<128, true,  true ><<<NT, 512, 0, stream>>>(xb, Wt1, b1, offs, srcSp, hb, nullptr);
    k_fused<64,  false, false><<<NT, 512, 0, stream>>>(hb, Wt2, b2, offs, srcSp, nullptr, out);
}

// Round 13
// 298.171 us; speedup vs baseline: 4.3155x; 4.3155x over previous
//
#include <hip/hip_runtime.h>

#define N_NODES 50000
#define N_EDGES 800000
#define R_REL   8
#define NR      (N_NODES * R_REL)        // 400000
#define SCAN_CHUNK 2048
#define SCAN_NBLK  ((NR + SCAN_CHUNK - 1) / SCAN_CHUNK)   // 196

// bucketed CSR build
#define NBKT    196                      // buckets of 256 dst-nodes
#define BNSH    8                        // dst>>8 -> bucket
#define BKEYS   2048                     // keys per bucket (256 nodes x 8 rels)
#define BCAP    5120                     // record capacity per bucket (mean 4083, +16 sigma)
#define SLAB    2048                     // edges per bin-block
#define BINBLK  ((N_EDGES + SLAB - 1) / SLAB)  // 391

typedef float  f32x4  __attribute__((ext_vector_type(4)));
typedef __bf16 bf16x8 __attribute__((ext_vector_type(8)));

__device__ __forceinline__ unsigned short f2bf(float f) {
    unsigned int u = __float_as_uint(f);
    u = (u + 0x7FFFu + ((u >> 16) & 1u)) >> 16;   // RNE
    return (unsigned short)u;
}
__device__ __forceinline__ float bflo(unsigned int u) { return __uint_as_float(u << 16); }
__device__ __forceinline__ float bfhi(unsigned int u) { return __uint_as_float(u & 0xFFFF0000u); }

__device__ __forceinline__ void acc16m(float* a, uint4 u0, uint4 u1, float m) {
    a[0]  = fmaf(bflo(u0.x), m, a[0]);   a[1]  = fmaf(bfhi(u0.x), m, a[1]);
    a[2]  = fmaf(bflo(u0.y), m, a[2]);   a[3]  = fmaf(bfhi(u0.y), m, a[3]);
    a[4]  = fmaf(bflo(u0.z), m, a[4]);   a[5]  = fmaf(bfhi(u0.z), m, a[5]);
    a[6]  = fmaf(bflo(u0.w), m, a[6]);   a[7]  = fmaf(bfhi(u0.w), m, a[7]);
    a[8]  = fmaf(bflo(u1.x), m, a[8]);   a[9]  = fmaf(bfhi(u1.x), m, a[9]);
    a[10] = fmaf(bflo(u1.y), m, a[10]);  a[11] = fmaf(bfhi(u1.y), m, a[11]);
    a[12] = fmaf(bflo(u1.z), m, a[12]);  a[13] = fmaf(bfhi(u1.z), m, a[13]);
    a[14] = fmaf(bflo(u1.w), m, a[14]);  a[15] = fmaf(bfhi(u1.w), m, a[15]);
}

// ---------------- bucketed CSR build ----------------

__global__ __launch_bounds__(256) void k_binA(
    const int* __restrict__ src, const int* __restrict__ dst,
    const int* __restrict__ et, int* __restrict__ gcur,
    uint2* __restrict__ gbin)
{
    __shared__ int hist[NBKT];
    __shared__ int base[NBKT];
    const int t = threadIdx.x;
    const int e0 = blockIdx.x * SLAB;
    for (int i = t; i < NBKT; i += 256) hist[i] = 0;
    __syncthreads();
#pragma unroll
    for (int i = 0; i < SLAB / 256; ++i) {
        int e = e0 + i * 256 + t;
        if (e < N_EDGES) atomicAdd(&hist[dst[e] >> BNSH], 1);
    }
    __syncthreads();
    for (int i = t; i < NBKT; i += 256) {
        int h = hist[i];
        base[i] = (h > 0) ? atomicAdd(&gcur[i], h) : 0;
        hist[i] = 0;   // reuse as sub-cursor
    }
    __syncthreads();
#pragma unroll
    for (int i = 0; i < SLAB / 256; ++i) {
        int e = e0 + i * 256 + t;
        if (e < N_EDGES) {
            int d = dst[e];
            int b = d >> BNSH;
            int sub = atomicAdd(&hist[b], 1);
            gbin[b * BCAP + base[b] + sub] =
                make_uint2((unsigned)src[e], (unsigned)(d * 8 + et[e]));
        }
    }
}

__global__ __launch_bounds__(256) void k_bcount(
    const int* __restrict__ gcur, const uint2* __restrict__ gbin,
    int* __restrict__ cnt)
{
    __shared__ int lc[BKEYS];
    const int t = threadIdx.x;
    const int b = blockIdx.x;
    for (int i = t; i < BKEYS; i += 256) lc[i] = 0;
    __syncthreads();
    const int n = gcur[b];
    const uint2* rec = gbin + (size_t)b * BCAP;
    const int kbase = b * BKEYS;
    for (int j = t; j < n; j += 256)
        atomicAdd(&lc[rec[j].y - kbase], 1);
    __syncthreads();
    for (int i = t; i < BKEYS; i += 256) {
        int k = kbase + i;
        if (k < NR) cnt[k] = lc[i];
    }
}

__global__ __launch_bounds__(256) void k_bscat(
    const int* __restrict__ gcur, const uint2* __restrict__ gbin,
    const int* __restrict__ offs, int* __restrict__ srcS)
{
    __shared__ int cur[BKEYS];
    const int t = threadIdx.x;
    const int b = blockIdx.x;
    for (int i = t; i < BKEYS; i += 256) cur[i] = 0;
    __syncthreads();
    const int n = gcur[b];
    const uint2* rec = gbin + (size_t)b * BCAP;
    const int kbase = b * BKEYS;
    for (int j = t; j < n; j += 256) {
        uint2 r = rec[j];
        int sub = atomicAdd(&cur[r.y - kbase], 1);
        srcS[offs[r.y] + sub] = (int)r.x;
    }
}

// ---------------- scans (exclusive prefix over cnt) ----------------

__global__ void k_scan1(const int* __restrict__ cnt, int* __restrict__ offs,
                        int* __restrict__ bsum) {
    __shared__ int sd[256];
    int t = threadIdx.x;
    int base = blockIdx.x * SCAN_CHUNK + t * 8;
    int v[8];
    int tot = 0;
#pragma unroll
    for (int i = 0; i < 8; i++) {
        int idx = base + i;
        int xv = (idx < NR) ? cnt[idx] : 0;
        v[i] = tot;
        tot += xv;
    }
    sd[t] = tot;
    __syncthreads();
    for (int off = 1; off < 256; off <<= 1) {
        int y = (t >= off) ? sd[t - off] : 0;
        __syncthreads();
        sd[t] += y;
        __syncthreads();
    }
    int excl = sd[t] - tot;
#pragma unroll
    for (int i = 0; i < 8; i++) {
        int idx = base + i;
        if (idx < NR) offs[idx] = v[i] + excl;
    }
    if (t == 255) bsum[blockIdx.x] = sd[255];
}

__global__ void k_scan2(const int* __restrict__ bsum, int* __restrict__ bsum2) {
    __shared__ int sd[256];
    int t = threadIdx.x;
    int v = (t < SCAN_NBLK) ? bsum[t] : 0;
    sd[t] = v;
    __syncthreads();
    for (int off = 1; off < 256; off <<= 1) {
        int y = (t >= off) ? sd[t - off] : 0;
        __syncthreads();
        sd[t] += y;
        __syncthreads();
    }
    bsum2[t] = sd[t] - v;
}

__global__ void k_scan3(int* __restrict__ offs, const int* __restrict__ bsum2) {
    int t = threadIdx.x;
    int b = blockIdx.x;
    int add = bsum2[b];
    int base = b * SCAN_CHUNK + t * 8;
#pragma unroll
    for (int i = 0; i < 8; i++) {
        int idx = base + i;
        if (idx < NR) offs[idx] += add;
    }
    if (b == 0 && t == 0) offs[NR] = N_EDGES;
}

// ---------------- converts ----------------

__global__ void k_cvt_x(const float* __restrict__ x, unsigned short* __restrict__ xb, int n4) {
    int i = blockIdx.x * 256 + threadIdx.x;
    if (i < n4) {
        float4 v = *(const float4*)(x + (size_t)i * 4);
        ushort4 o;
        o.x = f2bf(v.x); o.y = f2bf(v.y); o.z = f2bf(v.z); o.w = f2bf(v.w);
        *(ushort4*)(xb + (size_t)i * 4) = o;
    }
}

// Fragment-ordered weight packing:
// WtP[(((seg*4 + kk)*NBt + nb)*64 + lane)*8 + j] = B[seg][n=nb*16+(lane&15)][k=kk*32+(lane>>4)*8+j]
#define W1_ELEMS (9 * 128 * 128)   // NBt=8
#define W2_ELEMS (9 * 64 * 128)    // NBt=4
__global__ void k_wprep_all(const float* __restrict__ root1, const float* __restrict__ W1,
                            const float* __restrict__ root2, const float* __restrict__ W2,
                            unsigned short* __restrict__ Wt1, unsigned short* __restrict__ Wt2) {
    int idx = blockIdx.x * 256 + threadIdx.x;
    if (idx < W1_ELEMS) {
        int j    = idx & 7;
        int lane = (idx >> 3) & 63;
        int r    = idx >> 9;
        int nb   = r & 7;        // NBt = 8
        int r2   = r >> 3;
        int kk   = r2 & 3;
        int seg  = r2 >> 2;
        int k = kk * 32 + (lane >> 4) * 8 + j;
        int n = nb * 16 + (lane & 15);
        float v = (seg == 0) ? root1[k * 128 + n] : W1[((seg - 1) * 128 + k) * 128 + n];
        Wt1[idx] = f2bf(v);
    } else if (idx < W1_ELEMS + W2_ELEMS) {
        int i2   = idx - W1_ELEMS;
        int j    = i2 & 7;
        int lane = (i2 >> 3) & 63;
        int r    = i2 >> 9;
        int nb   = r & 3;        // NBt = 4
        int r2   = r >> 2;
        int kk   = r2 & 3;
        int seg  = r2 >> 2;
        int k = kk * 32 + (lane >> 4) * 8 + j;
        int n = nb * 16 + (lane & 15);
        float v = (seg == 0) ? root2[k * 64 + n] : W2[((seg - 1) * 128 + k) * 64 + n];
        Wt2[i2] = f2bf(v);
    }
}

// ---------------- fused gather + MFMA layer ----------------
// Block = 512 threads (8 waves), 16-node tile, 3125 blocks exact.
// Round-11 structure (proven 79 us) + 4-edge ILP in the gather chain:
// clamped index batch (dup loads are L1 hits), masked fmaf accumulate ->
// straggler rounds ceil(maxdeg/4) ~2.5 instead of ~4.5.
// Seg-0 (root) rows staged coalesced into As[0] by threads 0-127.
// ONE barrier; MFMA with fragment-ordered B (1 coalesced txn per B-frag).
// FOUT=128: wave w owns col-tile w. FOUT=64: waves 4-7 retire after barrier.

template <int FOUT, bool RELU, bool OUT_BF16>
__global__ __launch_bounds__(512) void k_fused(
    const unsigned short* __restrict__ xin,  // [N,128] bf16
    const unsigned short* __restrict__ WtP,  // fragment-ordered weights
    const float* __restrict__ bias,          // [FOUT]
    const int* __restrict__ offs,            // [NR+1]
    const int* __restrict__ srcS,            // [E]
    unsigned short* __restrict__ outb,       // [N,FOUT] bf16 (if OUT_BF16)
    float* __restrict__ outf)                // [N,FOUT] fp32 (else)
{
    constexpr int NBt = FOUT / 16;           // 8 (L1) / 4 (L2)
    __shared__ __align__(16) unsigned short As[9][16][136];  // 39.2 KB

    const int t = threadIdx.x;
    const int node0 = blockIdx.x * 16;

    // ---- seg-0 staging: threads 0-127, coalesced ----
    if (t < 128) {
        const int sr = t >> 3;
        const int sp = t & 7;
        const uint4* src = (const uint4*)(xin + (size_t)(node0 + sr) * 128 + sp * 16);
        uint4 r0 = src[0], r1 = src[1];
        uint4* d = (uint4*)&As[0][sr][sp * 16];
        d[0] = r0; d[1] = r1;
    }

    // ---- gather: one chain per thread (node, rel, quarter), 4-edge ILP ----
    {
        const int nl  = t >> 5;        // local node 0..15
        const int rel = (t >> 2) & 7;  // relation
        const int q   = t & 3;         // 32-feat quarter

        const int pair = (node0 + nl) * 8 + rel;
        const int beg = offs[pair];
        const int end = offs[pair + 1];
        const int deg = end - beg;

        const unsigned short* bx = xin + q * 32;
        float a[32];
#pragma unroll
        for (int i = 0; i < 32; ++i) a[i] = 0.f;

        if (deg > 0) {
            const int last = end - 1;
            for (int j = beg; j < end; j += 4) {
                int j1 = (j + 1 < end) ? j + 1 : last;
                int j2 = (j + 2 < end) ? j + 2 : last;
                int j3 = (j + 3 < end) ? j + 3 : last;
                int s0 = srcS[j];
                int s1 = srcS[j1];
                int s2 = srcS[j2];
                int s3 = srcS[j3];
                const uint4* p0 = (const uint4*)(bx + (size_t)s0 * 128);
                const uint4* p1 = (const uint4*)(bx + (size_t)s1 * 128);
                const uint4* p2 = (const uint4*)(bx + (size_t)s2 * 128);
                const uint4* p3 = (const uint4*)(bx + (size_t)s3 * 128);
                uint4 a0 = p0[0], a1 = p0[1], a2 = p0[2], a3 = p0[3];
                uint4 b0 = p1[0], b1 = p1[1], b2 = p1[2], b3 = p1[3];
                uint4 c0 = p2[0], c1 = p2[1], c2 = p2[2], c3 = p2[3];
                uint4 d0 = p3[0], d1 = p3[1], d2 = p3[2], d3 = p3[3];
                float m1 = (j + 1 < end) ? 1.f : 0.f;
                float m2 = (j + 2 < end) ? 1.f : 0.f;
                float m3 = (j + 3 < end) ? 1.f : 0.f;
                acc16m(a,      a0, a1, 1.f);
                acc16m(a + 16, a2, a3, 1.f);
                acc16m(a,      b0, b1, m1);
                acc16m(a + 16, b2, b3, m1);
                acc16m(a,      c0, c1, m2);
                acc16m(a + 16, c2, c3, m2);
                acc16m(a,      d0, d1, m3);
                acc16m(a + 16, d2, d3, m3);
            }
        }

        float scl = 1.f / (float)(deg > 1 ? deg : 1);
        unsigned int pk[16];
#pragma unroll
        for (int i = 0; i < 16; ++i)
            pk[i] = (unsigned int)f2bf(a[i * 2] * scl) |
                    ((unsigned int)f2bf(a[i * 2 + 1] * scl) << 16);
        uint4* d = (uint4*)&As[1 + rel][nl][q * 32];
        d[0] = make_uint4(pk[0],  pk[1],  pk[2],  pk[3]);
        d[1] = make_uint4(pk[4],  pk[5],  pk[6],  pk[7]);
        d[2] = make_uint4(pk[8],  pk[9],  pk[10], pk[11]);
        d[3] = make_uint4(pk[12], pk[13], pk[14], pk[15]);
    }

    __syncthreads();   // all 9 As slabs ready (the only barrier)

    // ---- MFMA phase: wave w owns col-tile w ----
    const int lane = t & 63;
    const int w = t >> 6;
    if (w >= NBt) return;            // FOUT=64: waves 4-7 done (no barriers after)
    const int quad = lane >> 4;
    const int tc = lane & 15;

    f32x4 acc = (f32x4){0.f, 0.f, 0.f, 0.f};
    const bf16x8* Bp = (const bf16x8*)WtP;

#pragma unroll
    for (int seg = 0; seg < 9; ++seg) {
        const unsigned short* Arow = &As[seg][tc][0];
#pragma unroll
        for (int kk = 0; kk < 4; ++kk) {
            bf16x8 af = *(const bf16x8*)(Arow + kk * 32 + quad * 8);
            bf16x8 bf = Bp[((seg * 4 + kk) * NBt + w) * 64 + lane];
            acc = __builtin_amdgcn_mfma_f32_16x16x32_bf16(af, bf, acc, 0, 0, 0);
        }
    }

    // epilogue: D layout col = lane&15, row = quad*4 + reg
    const int col = w * 16 + tc;
    const float bs = bias[col];
#pragma unroll
    for (int i = 0; i < 4; ++i) {
        int r = node0 + quad * 4 + i;
        float v = acc[i] + bs;
        if (RELU) v = fmaxf(v, 0.f);
        if (OUT_BF16) outb[(size_t)r * FOUT + col] = f2bf(v);
        else          outf[(size_t)r * FOUT + col] = v;
    }
}

// ---------------- launch ----------------

extern "C" void kernel_launch(void* const* d_in, const int* in_sizes, int n_in,
                              void* d_out, int out_size, void* d_ws, size_t ws_size,
                              hipStream_t stream) {
    const float* x     = (const float*)d_in[0];
    const int*   ei    = (const int*)d_in[1];  // [2][E]: row0=src, row1=dst
    const int*   et    = (const int*)d_in[2];  // [E]
    const float* W1    = (const float*)d_in[3];
    const float* root1 = (const float*)d_in[4];
    const float* b1    = (const float*)d_in[5];
    const float* W2    = (const float*)d_in[6];
    const float* root2 = (const float*)d_in[7];
    const float* b2    = (const float*)d_in[8];
    float* out = (float*)d_out;

    int* ws     = (int*)d_ws;
    int* cnt    = ws;                  // NR        (reused for Wt1 after scan1)
    int* offs   = cnt + NR;            // NR+128
    int* wt2buf = offs + NR + 128;     // NR        (holds Wt2, 144 KB)
    int* bsum   = wt2buf + NR;         // 256
    int* bsum2  = bsum + 256;          // 256
    int* gcur   = bsum2 + 256;         // 256
    int* srcS   = gcur + 256;          // E
    unsigned short* xb  = (unsigned short*)(srcS + N_EDGES); // [N,128] bf16 (12.8 MB)
    unsigned short* hb  = xb + (size_t)N_NODES * 128;        // [N,128] bf16 (12.8 MB)
    uint2* gbin = (uint2*)(hb + (size_t)N_NODES * 128);      // 8.03 MB
    unsigned short* Wt1 = (unsigned short*)cnt;
    unsigned short* Wt2 = (unsigned short*)wt2buf;
    // total ws usage: ~8 MB ints + 12.8 + 12.8 + 8 = ~42 MB (ws = 256 MiB)

    hipMemsetAsync(gcur, 0, 256 * sizeof(int), stream);
    k_binA<<<BINBLK, 256, 0, stream>>>(ei, ei + N_EDGES, et, gcur, gbin);
    k_bcount<<<NBKT, 256, 0, stream>>>(gcur, gbin, cnt);
    k_scan1<<<SCAN_NBLK, 256, 0, stream>>>(cnt, offs, bsum);
    k_scan2<<<1, 256, 0, stream>>>(bsum, bsum2);
    k_scan3<<<SCAN_NBLK, 256, 0, stream>>>(offs, bsum2);
    k_bscat<<<NBKT, 256, 0, stream>>>(gcur, gbin, offs, srcS);

    // cnt dead after scan1 -> Wt1 overwrites; wt2buf never aliased
    k_wprep_all<<<(W1_ELEMS + W2_ELEMS + 255) / 256, 256, 0, stream>>>(
        root1, W1, root2, W2, Wt1, Wt2);
    k_cvt_x<<<(N_NODES * 32 + 255) / 256, 256, 0, stream>>>(x, xb, N_NODES * 32);

    const int NT = N_NODES / 16;  // 3125 exactly

    k_fused<128, true,  true ><<<NT, 512, 0, stream>>>(xb, Wt1, b1, offs, srcS, hb, nullptr);
    k_fused<64,  false, false><<<NT, 512, 0, stream>>>(hb, Wt2, b2, offs, srcS, nullptr, out);
}